// Round 2
// baseline (103.800 us; speedup 1.0000x reference)
//
#include <hip/hip_runtime.h>
#include <stdint.h>

// Log-sparse causal attention, B=4 L=2048 H=8 E=D=64, fp32 in/out.
// Allowed distances delta = q - j (17 of them):
//   window {0..5} U log-sparse {6,7,9,13,21,37,69,133,261,517,1029}
// Each query attends <=17 keys -> direct sparse gather, no score matrix.

static constexpr int Bn = 4, Ln = 2048, Hn = 8, En = 64;
static constexpr int NDELTA = 17;

__global__ __launch_bounds__(256) void logsparse_attn_kernel(
    const float* __restrict__ Q,
    const float* __restrict__ K,
    const float* __restrict__ V,
    float* __restrict__ O)
{
    constexpr int deltas[NDELTA] = {0,1,2,3,4,5,6,7,9,13,21,37,69,133,261,517,1029};

    const int t   = blockIdx.x * 256 + threadIdx.x;
    const int sub = t & 15;         // 16 lanes per query, 4 dims each
    const int qid = t >> 4;         // [0, B*H*L)
    const int q   = qid & (Ln - 1);
    const int bh  = qid >> 11;      // [0, 32)
    const int b   = bh >> 3;
    const int h   = bh & 7;

    // row j of head (b,h) starts at ((b*Ln + j)*Hn + h)*En
    const size_t bhBase = ((size_t)b * Ln * Hn + (size_t)h) * (size_t)En;
    const size_t rowQ   = bhBase + (size_t)q * (Hn * En);

    // ---- load Q chunk (4 floats), fold scale = 1/sqrt(64) = 0.125 ----
    float4 qv = *(const float4*)(Q + rowQ + sub * 4);
    qv.x *= 0.125f; qv.y *= 0.125f; qv.z *= 0.125f; qv.w *= 0.125f;

    // ---- 17 sparse dot products ----
    float sc[NDELTA];
    #pragma unroll
    for (int d = 0; d < NDELTA; ++d) {
        const int j  = q - deltas[d];
        const int jc = (j < 0) ? 0 : j;
        const float4 kv = *(const float4*)(K + bhBase + (size_t)jc * (Hn * En) + sub * 4);
        float s = qv.x * kv.x + qv.y * kv.y + qv.z * kv.z + qv.w * kv.w;
        // butterfly reduce across the 16-lane group (all lanes get the sum)
        s += __shfl_xor(s, 1);
        s += __shfl_xor(s, 2);
        s += __shfl_xor(s, 4);
        s += __shfl_xor(s, 8);
        sc[d] = (j < 0) ? -__builtin_inff() : s;
    }

    // ---- softmax over the 17 scores (delta=0 always valid -> finite max) ----
    float m = sc[0];
    #pragma unroll
    for (int d = 1; d < NDELTA; ++d) m = fmaxf(m, sc[d]);
    float p[NDELTA];
    float sum = 0.0f;
    #pragma unroll
    for (int d = 0; d < NDELTA; ++d) {
        p[d] = __expf(sc[d] - m);   // exp(-inf) = 0 for masked-out (j<0)
        sum += p[d];
    }
    const float inv = 1.0f / sum;

    // ---- weighted sum of V rows (normalize at store) ----
    float ax = 0.f, ay = 0.f, az = 0.f, aw = 0.f;
    #pragma unroll
    for (int d = 0; d < NDELTA; ++d) {
        const int j  = q - deltas[d];
        const int jc = (j < 0) ? 0 : j;     // p[d]==0 when j<0, so clamp is safe
        const float4 vv = *(const float4*)(V + bhBase + (size_t)jc * (Hn * En) + sub * 4);
        const float w = p[d];
        ax = fmaf(w, vv.x, ax);
        ay = fmaf(w, vv.y, ay);
        az = fmaf(w, vv.z, az);
        aw = fmaf(w, vv.w, aw);
    }

    float4 o;
    o.x = ax * inv; o.y = ay * inv; o.z = az * inv; o.w = aw * inv;
    *(float4*)(O + rowQ + sub * 4) = o;
}

extern "C" void kernel_launch(void* const* d_in, const int* in_sizes, int n_in,
                              void* d_out, int out_size, void* d_ws, size_t ws_size,
                              hipStream_t stream) {
    const float* Q = (const float*)d_in[0];
    const float* K = (const float*)d_in[1];
    const float* V = (const float*)d_in[2];
    float* O = (float*)d_out;

    const int total_threads = Bn * Hn * Ln * 16;   // 16 lanes per query
    logsparse_attn_kernel<<<total_threads / 256, 256, 0, stream>>>(Q, K, V, O);
}